// Round 1
// baseline (72.590 us; speedup 1.0000x reference)
//
#include <hip/hip_runtime.h>
#include <math.h>

// Kuramoto fp8-MFMA, round 10: FUSE pack_k into the main kernel, drop d_ws.
// R6/R9 main loop preserved byte-for-byte (measured best 70.9-71.4 us).
// Change: K fp32->fp8 frag-order conversion moves in-kernel, but UNLIKE R8
// (scattered 8B frag-order global reads on the critical path, +4.8us) the
// global reads here are fully coalesced (thread = contiguous float8; 512
// threads = 16KB/sweep, 16 sweeps = 256KB) and the frag-order permutation
// happens via LDS scatter writes (ds_write_b64, ~4-way worst-case conflict,
// one-time prologue). Waves then fetch kf[][] frags with conflict-free
// ds_read_b64. Removes: pack_k launch, inter-kernel drain, kf8 global
// round-trip, and ALL workspace use (the harness poisons d_ws with 256MB
// fills at 40us each -- if any of that is on the timed path it goes away).
//
// GEMM (transposed): G^T = K . S^T; A = K fp8 (VGPR-resident frags), B = staged
// sin/cos fp8. D[row=4q+r -> osc-in-tile][col=l15 -> batch].
// Staging unit u (16B) = [S(8 osc)|C(8 osc)], phys = u ^ l15 swizzle: one
// ds_read_b128 -> long2 {Bs,Bc} used directly as MFMA B-operands.
// Rotation update: small-angle poly (|d|<=0.06, err ~6e-9), no in-loop trans.
// Conversion math identical to pack_k (same cvt_pk_fp8_f32 sequence) ->
// absmax unchanged at 0.015625 (1 bf16 ulp floor).

typedef __attribute__((ext_vector_type(4))) float f32x4;
typedef __attribute__((ext_vector_type(2))) long long2_t;

constexpr int N       = 256;
constexpr int RB      = 16;     // batch rows per block -> 64 blocks (structural cap)
constexpr int STEPS   = 10;
constexpr int WAVES   = 8;
constexpr int THREADS = WAVES * 64;
constexpr float DT    = 0.1f;
constexpr float TWO_PI     = 6.28318530717958648f;
constexpr float INV_TWO_PI = 0.15915494309189535f;

__global__ __launch_bounds__(THREADS, 2)
void kuramoto_r10(const float* __restrict__ theta0,
                  const float* __restrict__ Kmat,
                  const float* __restrict__ omega,
                  const float* __restrict__ kglob,
                  float* __restrict__ theta_out,
                  float* __restrict__ coh_out)
{
    // KF: frag-ordered fp8 K, 64KB. unit id = T*512 + c*64 + (16q+l15),
    // 8B each: K[16T+l15][32c+8q .. +8). Same layout pack_k produced in ws.
    __shared__ __align__(16) unsigned char KF[N * N];
    // [buf][row l15 * 512B]; 32 units/row of 16B = [S(8)|C(8)]; phys = u ^ l15.
    __shared__ __align__(16) unsigned char SC[2][RB * 512];
    __shared__ float redS[RB][WAVES], redC[RB][WAVES];

    const int tid  = threadIdx.x;
    const int wv   = tid >> 6;      // wave -> osc slab [32wv, 32wv+32), tiles 2wv, 2wv+1
    const int lane = tid & 63;
    const int q    = lane >> 4;
    const int l15  = lane & 15;     // batch-in-block (B-frag n / D col)
    const int b0   = blockIdx.x * RB;

    const float kgn = kglob[0] * (1.0f / 256.0f);

    // ---- rotation state: 8 osc/thread (t=0,1; r=0..3 at osc 32wv+16t+4q+r) ----
    // Issue these global loads first; sincos + K-conversion overlap their latency.
    float th[8], om[8], sn[8], cs[8];
#pragma unroll
    for (int t = 0; t < 2; ++t) {
        const int ob = 32 * wv + 16 * t + 4 * q;
        float4 t4 = *(const float4*)(theta0 + (size_t)(b0 + l15) * N + ob);
        float4 o4 = *(const float4*)(omega + ob);
        th[4*t+0] = t4.x; th[4*t+1] = t4.y; th[4*t+2] = t4.z; th[4*t+3] = t4.w;
        om[4*t+0] = o4.x; om[4*t+1] = o4.y; om[4*t+2] = o4.z; om[4*t+3] = o4.w;
    }

    // ---- in-block K fp32 -> fp8 frag-order (coalesced reads, LDS scatter) ----
    // float8 index g: row = g>>5, cols 8*(g&31)..+8. Read is CONTIGUOUS in g
    // (Kmat + g*8 floats) -> perfectly coalesced. Write goes to frag unit
    // id = T*512 + c*64 + 16q + l15 with T=row>>4, c=u8>>2, q=u8&3, l15=row&15.
#pragma unroll 4
    for (int i = 0; i < 16; ++i) {
        const int g   = i * THREADS + tid;      // 0..8191
        const int row = g >> 5;
        const int u8  = g & 31;
        const float* src = Kmat + (size_t)g * 8;
        float4 lo = *(const float4*)src;
        float4 hi = *(const float4*)(src + 4);
        int w0 = __builtin_amdgcn_cvt_pk_fp8_f32(lo.x, lo.y, 0, false);
        w0     = __builtin_amdgcn_cvt_pk_fp8_f32(lo.z, lo.w, w0, true);
        int w1 = __builtin_amdgcn_cvt_pk_fp8_f32(hi.x, hi.y, 0, false);
        w1     = __builtin_amdgcn_cvt_pk_fp8_f32(hi.z, hi.w, w1, true);
        const int id = ((row >> 4) << 9) | ((u8 >> 2) << 6) | ((u8 & 3) << 4) | (row & 15);
        int2 outp; outp.x = w0; outp.y = w1;
        *(int2*)(KF + (size_t)id * 8) = outp;
    }

#pragma unroll
    for (int k = 0; k < 8; ++k)
        __sincosf(th[k], &sn[k], &cs[k]);

    __syncthreads();   // KF fully written before any wave reads its frags

    // ---- K frags from LDS: kf[t][c], conflict-free b64 reads ----
    long kf[2][8];
#pragma unroll
    for (int t = 0; t < 2; ++t) {
        const unsigned char* base = KF + (size_t)((2 * wv + t) * 512 + lane) * 8;
#pragma unroll
        for (int c = 0; c < 8; ++c)
            kf[t][c] = *(const long*)(base + (size_t)c * 512);
    }

    const int so = 4 * (q & 1);          // dword slot within unit half
    const int g0 = 4 * wv + (q >> 1);    // staging unit of tile t=0 (t adds 2)

    for (int s = 0; s < STEPS; ++s) {
        unsigned char* rowp = &SC[s & 1][l15 * 512];
        // ---- stage: pack 4 osc of S and C per tile, two b32 writes ----
#pragma unroll
        for (int t = 0; t < 2; ++t) {
            int spk = __builtin_amdgcn_cvt_pk_fp8_f32(sn[4*t+0], sn[4*t+1], 0, false);
            spk     = __builtin_amdgcn_cvt_pk_fp8_f32(sn[4*t+2], sn[4*t+3], spk, true);
            int cpk = __builtin_amdgcn_cvt_pk_fp8_f32(cs[4*t+0], cs[4*t+1], 0, false);
            cpk     = __builtin_amdgcn_cvt_pk_fp8_f32(cs[4*t+2], cs[4*t+3], cpk, true);
            const int base = (((g0 + 2 * t) ^ l15) << 4);
            *(int*)(rowp + base + so)     = spk;   // S half
            *(int*)(rowp + base + 8 + so) = cpk;   // C half
        }
        __syncthreads();   // single barrier/step; double buffer covers WAR

        // ---- GEMMs: one b128 -> {Bs,Bc}, 4 interleaved acc chains (dep dist 4) ----
        f32x4 aS[2], aC[2];
        aS[0] = (f32x4){0.f,0.f,0.f,0.f}; aS[1] = (f32x4){0.f,0.f,0.f,0.f};
        aC[0] = (f32x4){0.f,0.f,0.f,0.f}; aC[1] = (f32x4){0.f,0.f,0.f,0.f};
#pragma unroll
        for (int c = 0; c < 8; ++c) {
            long2_t v = *(const long2_t*)(rowp + ((((4 * c + q) ^ l15)) << 4));
            aS[0] = __builtin_amdgcn_mfma_f32_16x16x32_fp8_fp8(kf[0][c], v.x, aS[0], 0, 0, 0);
            aC[0] = __builtin_amdgcn_mfma_f32_16x16x32_fp8_fp8(kf[0][c], v.y, aC[0], 0, 0, 0);
            aS[1] = __builtin_amdgcn_mfma_f32_16x16x32_fp8_fp8(kf[1][c], v.x, aS[1], 0, 0, 0);
            aC[1] = __builtin_amdgcn_mfma_f32_16x16x32_fp8_fp8(kf[1][c], v.y, aC[1], 0, 0, 0);
        }

        // ---- rotation update (no transcendentals) ----
#pragma unroll
        for (int t = 0; t < 2; ++t)
#pragma unroll
            for (int r = 0; r < 4; ++r) {
                const int k = 4 * t + r;
                float coup = cs[k] * aS[t][r] - sn[k] * aC[t][r];
                float d  = DT * fmaf(kgn, coup, om[k]);
                float d2 = d * d;
                float sd = d * fmaf(d2, -1.0f / 6.0f, 1.0f);              // sin(d)
                float cd = fmaf(d2, fmaf(d2, 1.0f / 24.0f, -0.5f), 1.0f); // cos(d)
                float s2 = fmaf(sn[k], cd,  cs[k] * sd);
                float c2 = fmaf(cs[k], cd, -sn[k] * sd);
                sn[k] = s2; cs[k] = c2; th[k] += d;
            }
    }

    // ---- epilogue: wrap, float4 stores, coherence from live (s,c) ----
    float ps = 0.f, pc = 0.f;
#pragma unroll
    for (int t = 0; t < 2; ++t) {
        const int ob = 32 * wv + 16 * t + 4 * q;
        float4 outv;
        outv.x = fmaf(-TWO_PI, rintf(th[4*t+0] * INV_TWO_PI), th[4*t+0]);
        outv.y = fmaf(-TWO_PI, rintf(th[4*t+1] * INV_TWO_PI), th[4*t+1]);
        outv.z = fmaf(-TWO_PI, rintf(th[4*t+2] * INV_TWO_PI), th[4*t+2]);
        outv.w = fmaf(-TWO_PI, rintf(th[4*t+3] * INV_TWO_PI), th[4*t+3]);
        *(float4*)(theta_out + (size_t)(b0 + l15) * N + ob) = outv;
#pragma unroll
        for (int r = 0; r < 4; ++r) { ps += sn[4*t+r]; pc += cs[4*t+r]; }
    }
    ps += __shfl_xor(ps, 16, 64);  pc += __shfl_xor(pc, 16, 64);
    ps += __shfl_xor(ps, 32, 64);  pc += __shfl_xor(pc, 32, 64);
    if (q == 0) { redS[l15][wv] = ps; redC[l15][wv] = pc; }
    __syncthreads();
    if (tid < RB) {
        float S = 0.f, C = 0.f;
#pragma unroll
        for (int k = 0; k < WAVES; ++k) { S += redS[tid][k]; C += redC[tid][k]; }
        float sm = S * (1.0f / 256.0f);
        float cm = C * (1.0f / 256.0f);
        coh_out[b0 + tid] = sqrtf(sm * sm + cm * cm);
    }
}

extern "C" void kernel_launch(void* const* d_in, const int* in_sizes, int n_in,
                              void* d_out, int out_size, void* d_ws, size_t ws_size,
                              hipStream_t stream) {
    const float* theta0 = (const float*)d_in[0];
    const float* Kmat   = (const float*)d_in[1];
    const float* omega  = (const float*)d_in[2];
    const float* kglob  = (const float*)d_in[3];

    (void)d_ws; (void)ws_size;   // workspace intentionally unused (no pack pass)

    float* theta_out = (float*)d_out;            // 1024*256
    float* coh_out   = theta_out + 1024 * N;     // then 1024

    kuramoto_r10<<<dim3(1024 / RB), dim3(THREADS), 0, stream>>>(
        theta0, Kmat, omega, kglob, theta_out, coh_out);
}

// Round 2
// 70.919 us; speedup vs baseline: 1.0236x; 1.0236x over previous
//
#include <hip/hip_runtime.h>
#include <math.h>

// Kuramoto fp8-MFMA, round 11: latency attack. R10 post-mortem: kernel is
// latency-bound (1 block/CU, 2 waves/SIMD, serial per-step chain), and R10's
// fused K-conversion had a 32-way ds_write_b64 bank conflict (bank pair =
// 2*l15, constant across each K-row's 32 scatter writes).
// Changes vs R10 (data layouts of the measured-best R6 loop kept bit-identical):
//  1. 16 waves (1024 thr), 1 tile (16 osc) per wave: per-step chain halves
//     (16 MFMAs/wave vs 32, 4-osc update vs 8) and occupancy doubles to
//     4 waves/SIMD -> cross-wave latency hiding.
//  2. KF XOR-swizzle phys = id ^ ((id>>4)&15): conversion scatter becomes
//     2-way (free), frag reads stay spread (involution on both sides).
//  3. GEMM split into lo/hi-K chains (aS0/aS1, aC0/aC1), 4 interleaved
//     chains -> MFMA dep distance 4 preserved.
//
// GEMM (transposed): G^T = K . S^T; A = K fp8 (VGPR frags), B = staged
// sin/cos fp8. D[row=4q+r -> osc-in-tile][col=l15 -> batch].
// Staging unit u (16B) = [S(8 osc)|C(8 osc)], phys = u ^ l15 swizzle: one
// ds_read_b128 -> long2 {Bs,Bc} used directly as MFMA B-operands.
// Rotation update: small-angle poly (|d|<=0.06, err ~6e-9), no in-loop trans.
// absmax floor = 1 bf16 ulp (0.015625), fp8 quantization dominated.

typedef __attribute__((ext_vector_type(4))) float f32x4;
typedef __attribute__((ext_vector_type(2))) long long2_t;

constexpr int N       = 256;
constexpr int RB      = 16;     // batch rows per block -> 64 blocks (structural cap)
constexpr int STEPS   = 10;
constexpr int WAVES   = 16;
constexpr int THREADS = WAVES * 64;   // 1024
constexpr float DT    = 0.1f;
constexpr float TWO_PI     = 6.28318530717958648f;
constexpr float INV_TWO_PI = 0.15915494309189535f;

__global__ __launch_bounds__(THREADS)
void kuramoto_r11(const float* __restrict__ theta0,
                  const float* __restrict__ Kmat,
                  const float* __restrict__ omega,
                  const float* __restrict__ kglob,
                  float* __restrict__ theta_out,
                  float* __restrict__ coh_out)
{
    // KF: frag-ordered fp8 K, 64KB. logical unit id (8B) = T*512 + c*64 +
    // 16q + l15 holds K[16T+l15][32c+8q .. +8); phys = id ^ ((id>>4)&15).
    __shared__ __align__(16) unsigned char KF[N * N];
    // [buf][row l15 * 512B]; 32 units/row of 16B = [S(8)|C(8)]; phys = u ^ l15.
    __shared__ __align__(16) unsigned char SC[2][RB * 512];
    __shared__ float redS[RB][WAVES], redC[RB][WAVES];

    const int tid  = threadIdx.x;
    const int wv   = tid >> 6;      // wave -> osc tile [16wv, 16wv+16)
    const int lane = tid & 63;
    const int q    = lane >> 4;
    const int l15  = lane & 15;     // batch-in-block (B-frag n / D col)
    const int b0   = blockIdx.x * RB;

    const float kgn = kglob[0] * (1.0f / 256.0f);

    // ---- rotation state: 4 osc/thread at osc = 16wv + 4q + r ----
    float th[4], om[4], sn[4], cs[4];
    {
        const int ob = 16 * wv + 4 * q;
        float4 t4 = *(const float4*)(theta0 + (size_t)(b0 + l15) * N + ob);
        float4 o4 = *(const float4*)(omega + ob);
        th[0]=t4.x; th[1]=t4.y; th[2]=t4.z; th[3]=t4.w;
        om[0]=o4.x; om[1]=o4.y; om[2]=o4.z; om[3]=o4.w;
    }

    // ---- K fp32 -> fp8 frag-order (coalesced reads, swizzled LDS scatter) ----
    // float8 index g: row = g>>5, cols 8*(g&31)..+8 (contiguous read).
    // id = T*512 + c*64 + 16q' + l15' with T=row>>4, c=u8>>2, q'=u8&3,
    // l15'=row&15. phys = id ^ ((id>>4)&15): within a row, (4c+q') == u8, so
    // bank pair = 2*(l15' ^ (u8&15)) sweeps all 16 pairs twice -> 2-way (free).
#pragma unroll 4
    for (int i = 0; i < 8; ++i) {
        const int g   = i * THREADS + tid;      // 0..8191
        const int row = g >> 5;
        const int u8  = g & 31;
        const float* src = Kmat + (size_t)g * 8;
        float4 lo = *(const float4*)src;
        float4 hi = *(const float4*)(src + 4);
        int w0 = __builtin_amdgcn_cvt_pk_fp8_f32(lo.x, lo.y, 0, false);
        w0     = __builtin_amdgcn_cvt_pk_fp8_f32(lo.z, lo.w, w0, true);
        int w1 = __builtin_amdgcn_cvt_pk_fp8_f32(hi.x, hi.y, 0, false);
        w1     = __builtin_amdgcn_cvt_pk_fp8_f32(hi.z, hi.w, w1, true);
        const int id = ((row >> 4) << 9) | ((u8 >> 2) << 6) | ((u8 & 3) << 4) | (row & 15);
        const int ph = id ^ ((id >> 4) & 15);
        int2 outp; outp.x = w0; outp.y = w1;
        *(int2*)(KF + (size_t)ph * 8) = outp;
    }

#pragma unroll
    for (int k = 0; k < 4; ++k)
        __sincosf(th[k], &sn[k], &cs[k]);

    __syncthreads();   // KF fully written before any wave reads its frags

    // ---- K frags from LDS: kf[c] for tile wv, chunk c (swizzled reads) ----
    long kf[8];
#pragma unroll
    for (int c = 0; c < 8; ++c) {
        const int id = (wv << 9) | (c << 6) | lane;      // (id>>4)&15 == (4c+q)&15
        const int ph = id ^ ((id >> 4) & 15);
        kf[c] = *(const long*)(KF + (size_t)ph * 8);
    }

    const int so = 4 * (q & 1);        // dword slot within unit half
    const int su = 2 * wv + (q >> 1);  // staging unit of this thread's 4 osc

    for (int s = 0; s < STEPS; ++s) {
        unsigned char* rowp = &SC[s & 1][l15 * 512];
        // ---- stage: pack this thread's 4 osc of S and C, two b32 writes ----
        {
            int spk = __builtin_amdgcn_cvt_pk_fp8_f32(sn[0], sn[1], 0, false);
            spk     = __builtin_amdgcn_cvt_pk_fp8_f32(sn[2], sn[3], spk, true);
            int cpk = __builtin_amdgcn_cvt_pk_fp8_f32(cs[0], cs[1], 0, false);
            cpk     = __builtin_amdgcn_cvt_pk_fp8_f32(cs[2], cs[3], cpk, true);
            const int base = ((su ^ l15) << 4);
            *(int*)(rowp + base + so)     = spk;   // S half
            *(int*)(rowp + base + 8 + so) = cpk;   // C half
        }
        __syncthreads();   // single barrier/step; double buffer covers WAR

        // ---- GEMM: 4 interleaved chains (lo/hi K halves), dep distance 4 ----
        f32x4 aS0 = (f32x4){0.f,0.f,0.f,0.f}, aS1 = (f32x4){0.f,0.f,0.f,0.f};
        f32x4 aC0 = (f32x4){0.f,0.f,0.f,0.f}, aC1 = (f32x4){0.f,0.f,0.f,0.f};
#pragma unroll
        for (int c = 0; c < 4; ++c) {
            long2_t v1 = *(const long2_t*)(rowp + (((4*c +      q) ^ l15) << 4));
            long2_t v2 = *(const long2_t*)(rowp + (((4*c + 16 + q) ^ l15) << 4));
            aS0 = __builtin_amdgcn_mfma_f32_16x16x32_fp8_fp8(kf[c],   v1.x, aS0, 0, 0, 0);
            aC0 = __builtin_amdgcn_mfma_f32_16x16x32_fp8_fp8(kf[c],   v1.y, aC0, 0, 0, 0);
            aS1 = __builtin_amdgcn_mfma_f32_16x16x32_fp8_fp8(kf[c+4], v2.x, aS1, 0, 0, 0);
            aC1 = __builtin_amdgcn_mfma_f32_16x16x32_fp8_fp8(kf[c+4], v2.y, aC1, 0, 0, 0);
        }
        f32x4 aS = aS0 + aS1;
        f32x4 aC = aC0 + aC1;

        // ---- rotation update (no transcendentals) ----
#pragma unroll
        for (int r = 0; r < 4; ++r) {
            float coup = cs[r] * aS[r] - sn[r] * aC[r];
            float d  = DT * fmaf(kgn, coup, om[r]);
            float d2 = d * d;
            float sd = d * fmaf(d2, -1.0f / 6.0f, 1.0f);              // sin(d)
            float cd = fmaf(d2, fmaf(d2, 1.0f / 24.0f, -0.5f), 1.0f); // cos(d)
            float s2 = fmaf(sn[r], cd,  cs[r] * sd);
            float c2 = fmaf(cs[r], cd, -sn[r] * sd);
            sn[r] = s2; cs[r] = c2; th[r] += d;
        }
    }

    // ---- epilogue: wrap, float4 store, coherence from live (s,c) ----
    float ps = 0.f, pc = 0.f;
    {
        const int ob = 16 * wv + 4 * q;
        float4 outv;
        outv.x = fmaf(-TWO_PI, rintf(th[0] * INV_TWO_PI), th[0]);
        outv.y = fmaf(-TWO_PI, rintf(th[1] * INV_TWO_PI), th[1]);
        outv.z = fmaf(-TWO_PI, rintf(th[2] * INV_TWO_PI), th[2]);
        outv.w = fmaf(-TWO_PI, rintf(th[3] * INV_TWO_PI), th[3]);
        *(float4*)(theta_out + (size_t)(b0 + l15) * N + ob) = outv;
#pragma unroll
        for (int r = 0; r < 4; ++r) { ps += sn[r]; pc += cs[r]; }
    }
    ps += __shfl_xor(ps, 16, 64);  pc += __shfl_xor(pc, 16, 64);
    ps += __shfl_xor(ps, 32, 64);  pc += __shfl_xor(pc, 32, 64);
    if (q == 0) { redS[l15][wv] = ps; redC[l15][wv] = pc; }
    __syncthreads();
    if (tid < RB) {
        float S = 0.f, C = 0.f;
#pragma unroll
        for (int k = 0; k < WAVES; ++k) { S += redS[tid][k]; C += redC[tid][k]; }
        float sm = S * (1.0f / 256.0f);
        float cm = C * (1.0f / 256.0f);
        coh_out[b0 + tid] = sqrtf(sm * sm + cm * cm);
    }
}

extern "C" void kernel_launch(void* const* d_in, const int* in_sizes, int n_in,
                              void* d_out, int out_size, void* d_ws, size_t ws_size,
                              hipStream_t stream) {
    const float* theta0 = (const float*)d_in[0];
    const float* Kmat   = (const float*)d_in[1];
    const float* omega  = (const float*)d_in[2];
    const float* kglob  = (const float*)d_in[3];

    (void)d_ws; (void)ws_size;   // workspace intentionally unused

    float* theta_out = (float*)d_out;            // 1024*256
    float* coh_out   = theta_out + 1024 * N;     // then 1024

    kuramoto_r11<<<dim3(1024 / RB), dim3(THREADS), 0, stream>>>(
        theta0, Kmat, omega, kglob, theta_out, coh_out);
}